// Round 5
// baseline (216.713 us; speedup 1.0000x reference)
//
#include <hip/hip_runtime.h>
#include <math.h>

#define LN_EPS 1e-5f
#define SCALE_QK 0.17677669529663687f  // 1/sqrt(32)

using bf16x8 = __bf16 __attribute__((ext_vector_type(8)));
using f32x4 = float __attribute__((ext_vector_type(4)));

__device__ __forceinline__ ushort f2bf(float f) {
  unsigned u = __float_as_uint(f);
  u += 0x7fff + ((u >> 16) & 1);  // RNE
  return (ushort)(u >> 16);
}

__device__ __forceinline__ void gload_lds16(const ushort* g, ushort* l) {
  __builtin_amdgcn_global_load_lds((__attribute__((address_space(1))) void*)g,
                                   (__attribute__((address_space(3))) void*)l, 16, 0, 0);
}

// ---------------------------------------------------------------------------
// Merged prep: blocks 0-2047 cast x -> bf16 (4 float4/thread);
// 2048-2111 q_w, 2112-2239 kv_w, 2240-2303 out_w casts;
// 2304-2559 conv_w transpose (oc,ic,4,4) -> wTb[oc][pos*256+ic] bf16.
// ---------------------------------------------------------------------------
__global__ __launch_bounds__(256) void prep_kernel(
    const float* __restrict__ x, ushort* __restrict__ xb,
    const float* __restrict__ qw, const float* __restrict__ kvw,
    const float* __restrict__ ow, const float* __restrict__ cw,
    ushort* __restrict__ qwb, ushort* __restrict__ kvwb,
    ushort* __restrict__ owb, ushort* __restrict__ wTb) {
  int blk = blockIdx.x, tid = threadIdx.x;
  if (blk < 2048) {
    int i = blk * 1024 + tid;
#pragma unroll
    for (int p = 0; p < 4; ++p) {
      float4 v = ((const float4*)x)[i + p * 256];
      ushort4 o = {f2bf(v.x), f2bf(v.y), f2bf(v.z), f2bf(v.w)};
      ((ushort4*)xb)[i + p * 256] = o;
    }
  } else if (blk < 2304) {
    int b2 = blk - 2048;
    const float* src;
    ushort* dst;
    int i;
    if (b2 < 64) { src = qw; dst = qwb; i = b2 * 256 + tid; }
    else if (b2 < 192) { src = kvw; dst = kvwb; i = (b2 - 64) * 256 + tid; }
    else { src = ow; dst = owb; i = (b2 - 192) * 256 + tid; }
    float4 v = ((const float4*)src)[i];
    ushort4 o = {f2bf(v.x), f2bf(v.y), f2bf(v.z), f2bf(v.w)};
    ((ushort4*)dst)[i] = o;
  } else {
    int oc = blk - 2304, ic = tid;
    const float* src = cw + (size_t)oc * 4096 + ic * 16;
#pragma unroll
    for (int pos = 0; pos < 16; ++pos)
      wTb[(size_t)oc * 4096 + pos * 256 + ic] = f2bf(src[pos]);
  }
}

// ---------------------------------------------------------------------------
// LDS-staged MFMA GEMM (used for conv patch-GEMM and KV projection).
// Block tile 128x64, 4 waves, BK=32, global_load_lds staging.
// OUTMODE 0: fp32 C[row][Nld] at z*zstride (conv split-K partials)
// OUTMODE 2: KV: col<256 -> K bf16 aux[b*256+m][256];
//                col>=256 -> vT bf16 aux2[((b*8+h)*32+d)*256+m], packed x4 rows
// ---------------------------------------------------------------------------
template <bool CONV, bool BIAS, int OUTMODE>
__global__ __launch_bounds__(256) void mfma_gemm(const ushort* __restrict__ A,
                                                 const ushort* __restrict__ Bw,
                                                 const float* __restrict__ bias,
                                                 float* __restrict__ C,
                                                 ushort* __restrict__ aux,
                                                 ushort* __restrict__ aux2, int Kld,
                                                 int Kslice, int Nld, size_t zstride) {
  __shared__ __attribute__((aligned(16))) ushort As[128 * 32];
  __shared__ __attribute__((aligned(16))) ushort Bs[64 * 32];
  int tid = threadIdx.x;
  int lane = tid & 63, w = tid >> 6;
  int m0 = blockIdx.y * 128, n0 = blockIdx.x * 64;
  int kbase = blockIdx.z * Kslice;
  int arow0 = w * 16 + (lane >> 2);
  int acol = (lane & 3) * 8;
  f32x4 acc[2][4];
#pragma unroll
  for (int i = 0; i < 2; ++i)
#pragma unroll
    for (int j = 0; j < 4; ++j) acc[i][j] = (f32x4){0.f, 0.f, 0.f, 0.f};

  for (int k0 = 0; k0 < Kslice; k0 += 32) {
    int kg = kbase + k0;
    __syncthreads();
#pragma unroll
    for (int t = 0; t < 2; ++t) {
      int row = arow0 + t * 64;
      const ushort* src;
      if (CONV) {
        int m = m0 + row;
        int b = m >> 8, mm = m & 255;
        int oh = mm >> 4, ow = mm & 15;
        int k = kg + acol;
        int pos = k >> 8, ic = k & 255;
        int n = ((oh << 2) + (pos >> 2)) * 64 + (ow << 2) + (pos & 3);
        src = A + ((size_t)(b * 4096 + n) * 256 + ic);
      } else {
        src = A + ((size_t)(m0 + row) * Kld + kg + acol);
      }
      gload_lds16(src, &As[t * 2048 + w * 512]);
    }
    {
      const ushort* srcb = Bw + ((size_t)(n0 + w * 16 + (lane >> 2)) * Kld + kg + acol);
      gload_lds16(srcb, &Bs[w * 512]);
    }
    __syncthreads();
    int qk = (lane >> 4) * 8, l15 = lane & 15;
    bf16x8 a0 = *(const bf16x8*)&As[(w * 32 + l15) * 32 + qk];
    bf16x8 a1 = *(const bf16x8*)&As[(w * 32 + 16 + l15) * 32 + qk];
#pragma unroll
    for (int j = 0; j < 4; ++j) {
      bf16x8 bj = *(const bf16x8*)&Bs[(j * 16 + l15) * 32 + qk];
      acc[0][j] = __builtin_amdgcn_mfma_f32_16x16x32_bf16(a0, bj, acc[0][j], 0, 0, 0);
      acc[1][j] = __builtin_amdgcn_mfma_f32_16x16x32_bf16(a1, bj, acc[1][j], 0, 0, 0);
    }
  }
  // epilogue: D row = w*32 + i*16 + (lane>>4)*4 + r, col = n0 + j*16 + (lane&15)
  int l15 = lane & 15, q = lane >> 4;
  if (OUTMODE == 0) {
    float* Cz = C + (size_t)blockIdx.z * zstride;
#pragma unroll
    for (int i = 0; i < 2; ++i) {
#pragma unroll
      for (int j = 0; j < 4; ++j) {
        int col = n0 + j * 16 + l15;
        float bv = BIAS ? bias[col] : 0.f;
#pragma unroll
        for (int r = 0; r < 4; ++r) {
          int row = m0 + w * 32 + i * 16 + q * 4 + r;
          Cz[(size_t)row * Nld + col] = acc[i][j][r] + bv;
        }
      }
    }
  } else {
#pragma unroll
    for (int i = 0; i < 2; ++i) {
      int rowb = m0 + w * 32 + i * 16 + q * 4;
      int b = rowb >> 8, mloc = rowb & 255;
#pragma unroll
      for (int j = 0; j < 4; ++j) {
        int col = n0 + j * 16 + l15;
        float bv = bias[col];
        if (col < 256) {  // K half (uniform per block)
#pragma unroll
          for (int r = 0; r < 4; ++r)
            aux[(size_t)(b * 256 + mloc + r) * 256 + col] = f2bf(acc[i][j][r] + bv);
        } else {  // V half -> transposed vT[((b*8+h)*32+d)][m], 4 m's packed
          int c2 = col - 256, h = c2 >> 5, d = c2 & 31;
          unsigned lo = (unsigned)f2bf(acc[i][j][0] + bv) |
                        ((unsigned)f2bf(acc[i][j][1] + bv) << 16);
          unsigned hi = (unsigned)f2bf(acc[i][j][2] + bv) |
                        ((unsigned)f2bf(acc[i][j][3] + bv) << 16);
          *(uint2*)(aux2 + ((size_t)((b * 8 + h) * 32 + d) * 256 + mloc)) =
              make_uint2(lo, hi);
        }
      }
    }
  }
}

// ---------------------------------------------------------------------------
// B-in-register MFMA GEMM for K=256, N=256: C = A[M][256] @ Bw[256][256]^T + b.
// No LDS, no barriers. Wave holds the whole 64-col B panel (32 bf16x8 frags),
// processes 4 m-tiles of 16 rows: 8 global b128 A-loads + 32 mfma each.
// Grid (4, M/256), 4 waves/block. F32OUT: fp32 else bf16 output.
// ---------------------------------------------------------------------------
template <bool F32OUT>
__global__ __launch_bounds__(256, 2) void breg_gemm(const ushort* __restrict__ A,
                                                    const ushort* __restrict__ Bw,
                                                    const float* __restrict__ bias,
                                                    float* __restrict__ Cf,
                                                    ushort* __restrict__ Cb) {
  int tid = threadIdx.x, lane = tid & 63, w = tid >> 6;
  int l15 = lane & 15, quad = lane >> 4;
  int n0 = blockIdx.x * 64;
  int m0 = blockIdx.y * 256 + w * 64;
  bf16x8 bfr[4][8];
  const ushort* bbase = Bw + (size_t)(n0 + l15) * 256 + quad * 8;
#pragma unroll
  for (int j = 0; j < 4; ++j)
#pragma unroll
    for (int kc = 0; kc < 8; ++kc)
      bfr[j][kc] = *(const bf16x8*)(bbase + (size_t)j * 16 * 256 + kc * 32);
  float bv[4];
#pragma unroll
  for (int j = 0; j < 4; ++j) bv[j] = bias[n0 + j * 16 + l15];

#pragma unroll
  for (int t = 0; t < 4; ++t) {
    const ushort* arow = A + (size_t)(m0 + t * 16 + l15) * 256 + quad * 8;
    bf16x8 af[8];
#pragma unroll
    for (int kc = 0; kc < 8; ++kc) af[kc] = *(const bf16x8*)(arow + kc * 32);
    f32x4 acc[4];
#pragma unroll
    for (int j = 0; j < 4; ++j) acc[j] = (f32x4){0.f, 0.f, 0.f, 0.f};
#pragma unroll
    for (int kc = 0; kc < 8; ++kc)
#pragma unroll
      for (int j = 0; j < 4; ++j)
        acc[j] = __builtin_amdgcn_mfma_f32_16x16x32_bf16(af[kc], bfr[j][kc], acc[j], 0, 0, 0);
#pragma unroll
    for (int j = 0; j < 4; ++j)
#pragma unroll
      for (int r = 0; r < 4; ++r) {
        int row = m0 + t * 16 + quad * 4 + r;
        int col = n0 + j * 16 + l15;
        float vv = acc[j][r] + bv[j];
        if (F32OUT) Cf[(size_t)row * 256 + col] = vv;
        else Cb[(size_t)row * 256 + col] = f2bf(vv);
      }
  }
}

// ---------------------------------------------------------------------------
// Fused split-K(8) reduce + conv bias + LayerNorm -> bf16. One block per token.
// ---------------------------------------------------------------------------
__global__ __launch_bounds__(256) void ln_fused(const float* __restrict__ part,
                                                const float* __restrict__ cb,
                                                const float* __restrict__ g,
                                                const float* __restrict__ bt,
                                                ushort* __restrict__ x1b) {
  int t = blockIdx.x, c = threadIdx.x;
  size_t idx = (size_t)t * 256 + c;
  float v = cb[c];
#pragma unroll
  for (int z = 0; z < 8; ++z) v += part[idx + (size_t)z * 524288];
  float s1 = v, s2 = v * v;
#pragma unroll
  for (int o = 32; o > 0; o >>= 1) {
    s1 += __shfl_down(s1, o, 64);
    s2 += __shfl_down(s2, o, 64);
  }
  __shared__ float r1[4], r2[4];
  __shared__ float mu_s, rstd_s;
  int wv = c >> 6, lane = c & 63;
  if (lane == 0) { r1[wv] = s1; r2[wv] = s2; }
  __syncthreads();
  if (c == 0) {
    float S1 = r1[0] + r1[1] + r1[2] + r1[3];
    float S2 = r2[0] + r2[1] + r2[2] + r2[3];
    float mu = S1 * (1.f / 256.f);
    float var = S2 * (1.f / 256.f) - mu * mu;
    mu_s = mu;
    rstd_s = rsqrtf(var + LN_EPS);
  }
  __syncthreads();
  x1b[idx] = f2bf((v - mu_s) * rstd_s * g[c] + bt[c]);
}

// ---------------------------------------------------------------------------
// MFMA flash attention: single-pass softmax (|scores| ~ O(1)), grid = b(8) x
// h(8) x chunk(16), 4 waves, each wave owns 64 q-rows as 4 tiles of 16.
// S^T = K@Q^T: all 64 of a lane's scores are one q-row (col=lane&15).
// Rolling qf prefetch; P round-trips LDS [q][m] stride 264; K,V frags in VGPRs.
// ---------------------------------------------------------------------------
__global__ __launch_bounds__(256) void attn_mfma(const ushort* __restrict__ qbb,
                                                 const ushort* __restrict__ kb,
                                                 const ushort* __restrict__ vT,
                                                 ushort* __restrict__ aob) {
  __shared__ __attribute__((aligned(16))) ushort P[4][16 * 264];
  int bid = blockIdx.x;  // 1024 = b(8) * h(8) * chunk(16)
  int chunk = bid & 15, h = (bid >> 4) & 7, b = bid >> 7;
  int tid = threadIdx.x, lane = tid & 63, w = tid >> 6;
  int l15 = lane & 15, quad = lane >> 4;
  ushort* Pw = &P[w][0];

  bf16x8 kf[16];
  const ushort* kbase = kb + ((size_t)(b * 256 + l15)) * 256 + h * 32 + quad * 8;
#pragma unroll
  for (int mt = 0; mt < 16; ++mt)
    kf[mt] = *(const bf16x8*)(kbase + (size_t)mt * 16 * 256);
  bf16x8 vf[2][8];
  const ushort* vbase = vT + (size_t)(b * 8 + h) * 32 * 256;
#pragma unroll
  for (int j = 0; j < 2; ++j)
#pragma unroll
    for (int kc = 0; kc < 8; ++kc)
      vf[j][kc] = *(const bf16x8*)(vbase + (size_t)(j * 16 + l15) * 256 + kc * 32 + quad * 8);

  const float Cc = SCALE_QK * 1.4426950408889634f;  // scale * log2(e)
  int q0base = b * 4096 + chunk * 256 + w * 64;
  const ushort* qptr = qbb + (size_t)(q0base + l15) * 256 + h * 32 + quad * 8;

  bf16x8 qn = *(const bf16x8*)qptr;  // prefetch tile 0
  for (int t = 0; t < 4; ++t) {
    bf16x8 qf = qn;
    if (t < 3) qn = *(const bf16x8*)(qptr + (size_t)(t + 1) * 16 * 256);
    int q0 = q0base + t * 16;
    float lsum = 0.f;
#pragma unroll
    for (int mt = 0; mt < 16; ++mt) {
      f32x4 st = __builtin_amdgcn_mfma_f32_16x16x32_bf16(
          kf[mt], qf, (f32x4){0.f, 0.f, 0.f, 0.f}, 0, 0, 0);
      unsigned u[4];
#pragma unroll
      for (int r = 0; r < 4; ++r) {
        float e = exp2f(st[r] * Cc);
        unsigned ur = (__float_as_uint(e) + 0x8000u) & 0xffff0000u;
        lsum += __uint_as_float(ur);  // sum the rounded value: consistent norm
        u[r] = ur;
      }
      unsigned lo = (u[0] >> 16) | u[1];
      unsigned hi = (u[2] >> 16) | u[3];
      *(uint2*)(Pw + l15 * 264 + mt * 16 + quad * 4) = make_uint2(lo, hi);
    }
    lsum += __shfl_xor(lsum, 16, 64);
    lsum += __shfl_xor(lsum, 32, 64);
    __threadfence_block();  // drain ds_writes before same-wave ds_reads
    f32x4 oacc[2] = {{0.f, 0.f, 0.f, 0.f}, {0.f, 0.f, 0.f, 0.f}};
#pragma unroll
    for (int kc = 0; kc < 8; ++kc) {
      bf16x8 pf = *(const bf16x8*)(Pw + l15 * 264 + kc * 32 + quad * 8);
      oacc[0] = __builtin_amdgcn_mfma_f32_16x16x32_bf16(pf, vf[0][kc], oacc[0], 0, 0, 0);
      oacc[1] = __builtin_amdgcn_mfma_f32_16x16x32_bf16(pf, vf[1][kc], oacc[1], 0, 0, 0);
    }
    float linv[4];
#pragma unroll
    for (int r = 0; r < 4; ++r) linv[r] = 1.0f / __shfl(lsum, quad * 4 + r, 64);
    ushort* ob = aob + (size_t)q0 * 256 + h * 32;
#pragma unroll
    for (int j = 0; j < 2; ++j)
#pragma unroll
      for (int r = 0; r < 4; ++r) {
        unsigned uo = __float_as_uint(oacc[j][r] * linv[r]) + 0x8000u;
        ob[(size_t)(quad * 4 + r) * 256 + j * 16 + l15] = (ushort)(uo >> 16);
      }
  }
}

// ---------------------------------------------------------------------------
extern "C" void kernel_launch(void* const* d_in, const int* in_sizes, int n_in,
                              void* d_out, int out_size, void* d_ws, size_t ws_size,
                              hipStream_t stream) {
  const float* x = (const float*)d_in[0];
  const float* conv_w = (const float*)d_in[1];
  const float* conv_b = (const float*)d_in[2];
  const float* ln_g = (const float*)d_in[3];
  const float* ln_b = (const float*)d_in[4];
  const float* kv_w = (const float*)d_in[5];
  const float* kv_b = (const float*)d_in[6];
  const float* q_w = (const float*)d_in[7];
  const float* q_b = (const float*)d_in[8];
  const float* out_w = (const float*)d_in[9];
  const float* out_b = (const float*)d_in[10];

  // workspace (~22.4 MB)
  ushort* xb = (ushort*)d_ws;                  // 8,388,608 bf16; aliased as aob later
  ushort* wTb = xb + 8388608;                  // 1,048,576 bf16
  ushort* qwb = wTb + 1048576;                 // 65,536
  ushort* kvwb = qwb + 65536;                  // 131,072
  ushort* owb = kvwb + 131072;                 // 65,536
  ushort* x1b = owb + 65536;                   // 524,288 bf16
  ushort* kb = x1b + 524288;                   // 524,288 bf16: K [b*256+m][256]
  ushort* vT = kb + 524288;                    // 524,288 bf16: V^T [((b*8+h)*32+d)][m]
  ushort* aob = xb;                            // attention out, reuses xb
  // d_out (33.55 MB fp32) doubles as scratch before the final projection:
  float* part = (float*)d_out;                 // 8 x 524,288 f32 conv partials
  ushort* qbb = (ushort*)((float*)d_out + 4194304);  // 8,388,608 bf16 Q

  prep_kernel<<<2560, 256, 0, stream>>>(x, xb, q_w, kv_w, out_w, conv_w,
                                        qwb, kvwb, owb, wTb);
  // conv as patch-GEMM, split-K=8 -> fp32 partials (in d_out)
  mfma_gemm<true, false, 0><<<dim3(4, 16, 8), 256, 0, stream>>>(
      xb, wTb, nullptr, part, nullptr, nullptr, 4096, 512, 256, 524288);
  // fused reduce + bias + LayerNorm -> x1b bf16
  ln_fused<<<2048, 256, 0, stream>>>(part, conv_b, ln_g, ln_b, x1b);
  // KV projection -> K bf16 (kb) + V^T bf16 (vT)
  mfma_gemm<false, true, 2><<<dim3(8, 16, 1), 256, 0, stream>>>(
      x1b, kvwb, kv_b, nullptr, kb, vT, 256, 256, 512, 0);
  // Q projection -> qbb bf16 (upper half of d_out)
  breg_gemm<false><<<dim3(4, 128), 256, 0, stream>>>(xb, qwb, q_b, nullptr, qbb);
  // MFMA flash attention -> aob bf16 (aliases xb; xb dead after Q proj)
  attn_mfma<<<1024, 256, 0, stream>>>(qbb, kb, vT, aob);
  // output projection -> d_out fp32 (overwrites the scratch halves)
  breg_gemm<true><<<dim3(4, 128), 256, 0, stream>>>(aob, owb, out_b, (float*)d_out, nullptr);
}

// Round 6
// 205.973 us; speedup vs baseline: 1.0521x; 1.0521x over previous
//
#include <hip/hip_runtime.h>
#include <math.h>

#define LN_EPS 1e-5f
#define SCALE_QK 0.17677669529663687f  // 1/sqrt(32)

using bf16x8 = __bf16 __attribute__((ext_vector_type(8)));
using f32x4 = float __attribute__((ext_vector_type(4)));

__device__ __forceinline__ ushort f2bf(float f) {
  unsigned u = __float_as_uint(f);
  u += 0x7fff + ((u >> 16) & 1);  // RNE
  return (ushort)(u >> 16);
}

__device__ __forceinline__ void gload_lds16(const ushort* g, ushort* l) {
  __builtin_amdgcn_global_load_lds((__attribute__((address_space(1))) void*)g,
                                   (__attribute__((address_space(3))) void*)l, 16, 0, 0);
}

// ---------------------------------------------------------------------------
// Merged prep: blocks 0-2047 cast x -> bf16 (4 float4/thread);
// 2048-2111 q_w, 2112-2239 kv_w, 2240-2303 out_w casts;
// 2304-2559 conv_w transpose (oc,ic,4,4) -> wTb[oc][pos*256+ic] bf16.
// ---------------------------------------------------------------------------
__global__ __launch_bounds__(256) void prep_kernel(
    const float* __restrict__ x, ushort* __restrict__ xb,
    const float* __restrict__ qw, const float* __restrict__ kvw,
    const float* __restrict__ ow, const float* __restrict__ cw,
    ushort* __restrict__ qwb, ushort* __restrict__ kvwb,
    ushort* __restrict__ owb, ushort* __restrict__ wTb) {
  int blk = blockIdx.x, tid = threadIdx.x;
  if (blk < 2048) {
    int i = blk * 1024 + tid;
#pragma unroll
    for (int p = 0; p < 4; ++p) {
      float4 v = ((const float4*)x)[i + p * 256];
      ushort4 o = {f2bf(v.x), f2bf(v.y), f2bf(v.z), f2bf(v.w)};
      ((ushort4*)xb)[i + p * 256] = o;
    }
  } else if (blk < 2304) {
    int b2 = blk - 2048;
    const float* src;
    ushort* dst;
    int i;
    if (b2 < 64) { src = qw; dst = qwb; i = b2 * 256 + tid; }
    else if (b2 < 192) { src = kvw; dst = kvwb; i = (b2 - 64) * 256 + tid; }
    else { src = ow; dst = owb; i = (b2 - 192) * 256 + tid; }
    float4 v = ((const float4*)src)[i];
    ushort4 o = {f2bf(v.x), f2bf(v.y), f2bf(v.z), f2bf(v.w)};
    ((ushort4*)dst)[i] = o;
  } else {
    int oc = blk - 2304, ic = tid;
    const float* src = cw + (size_t)oc * 4096 + ic * 16;
#pragma unroll
    for (int pos = 0; pos < 16; ++pos)
      wTb[(size_t)oc * 4096 + pos * 256 + ic] = f2bf(src[pos]);
  }
}

// ---------------------------------------------------------------------------
// LDS-staged MFMA GEMM (conv patch-GEMM and KV projection).
// Block tile 128x64, 4 waves, BK=32, global_load_lds staging.
// OUTMODE 0: fp32 C[row][Nld] at z*zstride (conv split-K partials)
// OUTMODE 2: KV: col<256 -> K bf16 aux[b*256+m][256];
//                col>=256 -> vT bf16 aux2[((b*8+h)*32+d)*256+m], packed x4 rows
// ---------------------------------------------------------------------------
template <bool CONV, bool BIAS, int OUTMODE>
__global__ __launch_bounds__(256) void mfma_gemm(const ushort* __restrict__ A,
                                                 const ushort* __restrict__ Bw,
                                                 const float* __restrict__ bias,
                                                 float* __restrict__ C,
                                                 ushort* __restrict__ aux,
                                                 ushort* __restrict__ aux2, int Kld,
                                                 int Kslice, int Nld, size_t zstride) {
  __shared__ __attribute__((aligned(16))) ushort As[128 * 32];
  __shared__ __attribute__((aligned(16))) ushort Bs[64 * 32];
  int tid = threadIdx.x;
  int lane = tid & 63, w = tid >> 6;
  int m0 = blockIdx.y * 128, n0 = blockIdx.x * 64;
  int kbase = blockIdx.z * Kslice;
  int arow0 = w * 16 + (lane >> 2);
  int acol = (lane & 3) * 8;
  f32x4 acc[2][4];
#pragma unroll
  for (int i = 0; i < 2; ++i)
#pragma unroll
    for (int j = 0; j < 4; ++j) acc[i][j] = (f32x4){0.f, 0.f, 0.f, 0.f};

  for (int k0 = 0; k0 < Kslice; k0 += 32) {
    int kg = kbase + k0;
    __syncthreads();
#pragma unroll
    for (int t = 0; t < 2; ++t) {
      int row = arow0 + t * 64;
      const ushort* src;
      if (CONV) {
        int m = m0 + row;
        int b = m >> 8, mm = m & 255;
        int oh = mm >> 4, ow = mm & 15;
        int k = kg + acol;
        int pos = k >> 8, ic = k & 255;
        int n = ((oh << 2) + (pos >> 2)) * 64 + (ow << 2) + (pos & 3);
        src = A + ((size_t)(b * 4096 + n) * 256 + ic);
      } else {
        src = A + ((size_t)(m0 + row) * Kld + kg + acol);
      }
      gload_lds16(src, &As[t * 2048 + w * 512]);
    }
    {
      const ushort* srcb = Bw + ((size_t)(n0 + w * 16 + (lane >> 2)) * Kld + kg + acol);
      gload_lds16(srcb, &Bs[w * 512]);
    }
    __syncthreads();
    int qk = (lane >> 4) * 8, l15 = lane & 15;
    bf16x8 a0 = *(const bf16x8*)&As[(w * 32 + l15) * 32 + qk];
    bf16x8 a1 = *(const bf16x8*)&As[(w * 32 + 16 + l15) * 32 + qk];
#pragma unroll
    for (int j = 0; j < 4; ++j) {
      bf16x8 bj = *(const bf16x8*)&Bs[(j * 16 + l15) * 32 + qk];
      acc[0][j] = __builtin_amdgcn_mfma_f32_16x16x32_bf16(a0, bj, acc[0][j], 0, 0, 0);
      acc[1][j] = __builtin_amdgcn_mfma_f32_16x16x32_bf16(a1, bj, acc[1][j], 0, 0, 0);
    }
  }
  int l15 = lane & 15, q = lane >> 4;
  if (OUTMODE == 0) {
    float* Cz = C + (size_t)blockIdx.z * zstride;
#pragma unroll
    for (int i = 0; i < 2; ++i) {
#pragma unroll
      for (int j = 0; j < 4; ++j) {
        int col = n0 + j * 16 + l15;
        float bv = BIAS ? bias[col] : 0.f;
#pragma unroll
        for (int r = 0; r < 4; ++r) {
          int row = m0 + w * 32 + i * 16 + q * 4 + r;
          Cz[(size_t)row * Nld + col] = acc[i][j][r] + bv;
        }
      }
    }
  } else {
#pragma unroll
    for (int i = 0; i < 2; ++i) {
      int rowb = m0 + w * 32 + i * 16 + q * 4;
      int b = rowb >> 8, mloc = rowb & 255;
#pragma unroll
      for (int j = 0; j < 4; ++j) {
        int col = n0 + j * 16 + l15;
        float bv = bias[col];
        if (col < 256) {  // K half
#pragma unroll
          for (int r = 0; r < 4; ++r)
            aux[(size_t)(b * 256 + mloc + r) * 256 + col] = f2bf(acc[i][j][r] + bv);
        } else {  // V half -> vT[((b*8+h)*32+d)][m]
          int c2 = col - 256, h = c2 >> 5, d = c2 & 31;
          unsigned lo = (unsigned)f2bf(acc[i][j][0] + bv) |
                        ((unsigned)f2bf(acc[i][j][1] + bv) << 16);
          unsigned hi = (unsigned)f2bf(acc[i][j][2] + bv) |
                        ((unsigned)f2bf(acc[i][j][3] + bv) << 16);
          *(uint2*)(aux2 + ((size_t)((b * 8 + h) * 32 + d) * 256 + mloc)) =
              make_uint2(lo, hi);
        }
      }
    }
  }
}

// ---------------------------------------------------------------------------
// B-in-register MFMA GEMM for K=256, N=256 (Q and out projections).
// ---------------------------------------------------------------------------
template <bool F32OUT>
__global__ __launch_bounds__(256, 2) void breg_gemm(const ushort* __restrict__ A,
                                                    const ushort* __restrict__ Bw,
                                                    const float* __restrict__ bias,
                                                    float* __restrict__ Cf,
                                                    ushort* __restrict__ Cb) {
  int tid = threadIdx.x, lane = tid & 63, w = tid >> 6;
  int l15 = lane & 15, quad = lane >> 4;
  int n0 = blockIdx.x * 64;
  int m0 = blockIdx.y * 256 + w * 64;
  bf16x8 bfr[4][8];
  const ushort* bbase = Bw + (size_t)(n0 + l15) * 256 + quad * 8;
#pragma unroll
  for (int j = 0; j < 4; ++j)
#pragma unroll
    for (int kc = 0; kc < 8; ++kc)
      bfr[j][kc] = *(const bf16x8*)(bbase + (size_t)j * 16 * 256 + kc * 32);
  float bv[4];
#pragma unroll
  for (int j = 0; j < 4; ++j) bv[j] = bias[n0 + j * 16 + l15];

#pragma unroll
  for (int t = 0; t < 4; ++t) {
    const ushort* arow = A + (size_t)(m0 + t * 16 + l15) * 256 + quad * 8;
    bf16x8 af[8];
#pragma unroll
    for (int kc = 0; kc < 8; ++kc) af[kc] = *(const bf16x8*)(arow + kc * 32);
    f32x4 acc[4];
#pragma unroll
    for (int j = 0; j < 4; ++j) acc[j] = (f32x4){0.f, 0.f, 0.f, 0.f};
#pragma unroll
    for (int kc = 0; kc < 8; ++kc)
#pragma unroll
      for (int j = 0; j < 4; ++j)
        acc[j] = __builtin_amdgcn_mfma_f32_16x16x32_bf16(af[kc], bfr[j][kc], acc[j], 0, 0, 0);
#pragma unroll
    for (int j = 0; j < 4; ++j)
#pragma unroll
      for (int r = 0; r < 4; ++r) {
        int row = m0 + t * 16 + quad * 4 + r;
        int col = n0 + j * 16 + l15;
        float vv = acc[j][r] + bv[j];
        if (F32OUT) Cf[(size_t)row * 256 + col] = vv;
        else Cb[(size_t)row * 256 + col] = f2bf(vv);
      }
  }
}

// ---------------------------------------------------------------------------
// Fused split-K(8) reduce + conv bias + LayerNorm -> bf16. One block per token.
// ---------------------------------------------------------------------------
__global__ __launch_bounds__(256) void ln_fused(const float* __restrict__ part,
                                                const float* __restrict__ cb,
                                                const float* __restrict__ g,
                                                const float* __restrict__ bt,
                                                ushort* __restrict__ x1b) {
  int t = blockIdx.x, c = threadIdx.x;
  size_t idx = (size_t)t * 256 + c;
  float v = cb[c];
#pragma unroll
  for (int z = 0; z < 8; ++z) v += part[idx + (size_t)z * 524288];
  float s1 = v, s2 = v * v;
#pragma unroll
  for (int o = 32; o > 0; o >>= 1) {
    s1 += __shfl_down(s1, o, 64);
    s2 += __shfl_down(s2, o, 64);
  }
  __shared__ float r1[4], r2[4];
  __shared__ float mu_s, rstd_s;
  int wv = c >> 6, lane = c & 63;
  if (lane == 0) { r1[wv] = s1; r2[wv] = s2; }
  __syncthreads();
  if (c == 0) {
    float S1 = r1[0] + r1[1] + r1[2] + r1[3];
    float S2 = r2[0] + r2[1] + r2[2] + r2[3];
    float mu = S1 * (1.f / 256.f);
    float var = S2 * (1.f / 256.f) - mu * mu;
    mu_s = mu;
    rstd_s = rsqrtf(var + LN_EPS);
  }
  __syncthreads();
  x1b[idx] = f2bf((v - mu_s) * rstd_s * g[c] + bt[c]);
}

// ---------------------------------------------------------------------------
// MFMA flash attention v4. Key fix vs v2/v3: K-head + V-head are staged into
// LDS ONCE PER BLOCK via global_load_lds (32 KB), then each wave extracts its
// register fragments from LDS. This cuts the per-wave/per-chunk redundant
// K/V global traffic from 134 MB to 33.5 MB (the round-5 bottleneck).
// Single-pass softmax (|s| ~ O(1)); exp via raw v_exp_f32; P packed with RNE
// (+0x8000 then perm) and summed pre-round (RNE is mean-zero vs stored P).
// ---------------------------------------------------------------------------
__global__ __launch_bounds__(256) void attn_mfma(const ushort* __restrict__ qbb,
                                                 const ushort* __restrict__ kb,
                                                 const ushort* __restrict__ vT,
                                                 ushort* __restrict__ aob) {
  // 33792 B: first 32 KB double as K/V staging, then becomes 4 P buffers.
  __shared__ __attribute__((aligned(16))) ushort sh[4 * 16 * 264];
  int bid = blockIdx.x;  // 1024 = b(8) * h(8) * chunk(16)
  int chunk = bid & 15, h = (bid >> 4) & 7, b = bid >> 7;
  int tid = threadIdx.x, lane = tid & 63, w = tid >> 6;
  int l15 = lane & 15, quad = lane >> 4;

  // ---- stage K-head -> sh[0..8192) as [m][32]; V-head -> sh[8192..16384) as [d][256]
  {
    const ushort* srcK = kb + (size_t)(b * 256 + w * 64 + (lane >> 2)) * 256 +
                         h * 32 + (lane & 3) * 8;
#pragma unroll
    for (int i = 0; i < 4; ++i)
      gload_lds16(srcK + (size_t)i * 16 * 256, &sh[(w * 64 + i * 16) * 32]);
    const ushort* srcV = vT + (size_t)((b * 8 + h) * 32 + w * 8 + (lane >> 5)) * 256 +
                         (lane & 31) * 8;
#pragma unroll
    for (int i = 0; i < 4; ++i)
      gload_lds16(srcV + (size_t)i * 2 * 256, &sh[8192 + (w * 8 + i * 2) * 256]);
  }
  __syncthreads();  // staging visible (drains vmcnt)
  // ---- extract register fragments (one-time; bank conflicts acceptable here)
  bf16x8 kf[16];
#pragma unroll
  for (int mt = 0; mt < 16; ++mt)
    kf[mt] = *(const bf16x8*)&sh[(mt * 16 + l15) * 32 + quad * 8];
  bf16x8 vf[2][8];
#pragma unroll
  for (int j = 0; j < 2; ++j)
#pragma unroll
    for (int kc = 0; kc < 8; ++kc)
      vf[j][kc] = *(const bf16x8*)&sh[8192 + (j * 16 + l15) * 256 + kc * 32 + quad * 8];
  __syncthreads();  // all frags extracted; sh now reusable as P buffers
  ushort* Pw = &sh[w * 16 * 264];

  const float Cc = SCALE_QK * 1.4426950408889634f;  // scale * log2(e)
  int q0base = b * 4096 + chunk * 256 + w * 64;

  for (int t = 0; t < 4; ++t) {
    int q0 = q0base + t * 16;
    bf16x8 qf = *(const bf16x8*)(qbb + (size_t)(q0 + l15) * 256 + h * 32 + quad * 8);
    float lsum = 0.f;
#pragma unroll
    for (int mt = 0; mt < 16; ++mt) {
      f32x4 st = __builtin_amdgcn_mfma_f32_16x16x32_bf16(
          kf[mt], qf, (f32x4){0.f, 0.f, 0.f, 0.f}, 0, 0, 0);
      unsigned u[4];
#pragma unroll
      for (int r = 0; r < 4; ++r) {
        float e = __builtin_amdgcn_exp2f(st[r] * Cc);
        lsum += e;  // pre-round sum; RNE of stored P is mean-zero vs this
        u[r] = __float_as_uint(e) + 0x8000u;
      }
      unsigned lo = (u[0] >> 16) | (u[1] & 0xffff0000u);  // v_perm pattern
      unsigned hi = (u[2] >> 16) | (u[3] & 0xffff0000u);
      *(uint2*)(Pw + l15 * 264 + mt * 16 + quad * 4) = make_uint2(lo, hi);
    }
    lsum += __shfl_xor(lsum, 16, 64);
    lsum += __shfl_xor(lsum, 32, 64);
    __builtin_amdgcn_s_waitcnt(0xc07f);  // lgkmcnt(0): drain ds_writes only
    f32x4 oacc[2] = {{0.f, 0.f, 0.f, 0.f}, {0.f, 0.f, 0.f, 0.f}};
#pragma unroll
    for (int kc = 0; kc < 8; ++kc) {
      bf16x8 pf = *(const bf16x8*)(Pw + l15 * 264 + kc * 32 + quad * 8);
      oacc[0] = __builtin_amdgcn_mfma_f32_16x16x32_bf16(pf, vf[0][kc], oacc[0], 0, 0, 0);
      oacc[1] = __builtin_amdgcn_mfma_f32_16x16x32_bf16(pf, vf[1][kc], oacc[1], 0, 0, 0);
    }
    float linv[4];
#pragma unroll
    for (int r = 0; r < 4; ++r) linv[r] = 1.0f / __shfl(lsum, quad * 4 + r, 64);
    ushort* ob = aob + (size_t)q0 * 256 + h * 32;
#pragma unroll
    for (int j = 0; j < 2; ++j)
#pragma unroll
      for (int r = 0; r < 4; ++r) {
        unsigned uo = __float_as_uint(oacc[j][r] * linv[r]) + 0x8000u;
        ob[(size_t)(quad * 4 + r) * 256 + j * 16 + l15] = (ushort)(uo >> 16);
      }
  }
}

// ---------------------------------------------------------------------------
extern "C" void kernel_launch(void* const* d_in, const int* in_sizes, int n_in,
                              void* d_out, int out_size, void* d_ws, size_t ws_size,
                              hipStream_t stream) {
  const float* x = (const float*)d_in[0];
  const float* conv_w = (const float*)d_in[1];
  const float* conv_b = (const float*)d_in[2];
  const float* ln_g = (const float*)d_in[3];
  const float* ln_b = (const float*)d_in[4];
  const float* kv_w = (const float*)d_in[5];
  const float* kv_b = (const float*)d_in[6];
  const float* q_w = (const float*)d_in[7];
  const float* q_b = (const float*)d_in[8];
  const float* out_w = (const float*)d_in[9];
  const float* out_b = (const float*)d_in[10];

  // workspace (~22.4 MB)
  ushort* xb = (ushort*)d_ws;                  // 8,388,608 bf16; aliased as aob later
  ushort* wTb = xb + 8388608;                  // 1,048,576 bf16
  ushort* qwb = wTb + 1048576;                 // 65,536
  ushort* kvwb = qwb + 65536;                  // 131,072
  ushort* owb = kvwb + 131072;                 // 65,536
  ushort* x1b = owb + 65536;                   // 524,288 bf16
  ushort* kb = x1b + 524288;                   // 524,288 bf16: K [b*256+m][256]
  ushort* vT = kb + 524288;                    // 524,288 bf16: V^T [((b*8+h)*32+d)][m]
  ushort* aob = xb;                            // attention out, reuses xb
  // d_out (33.55 MB fp32) doubles as scratch before the final projection:
  float* part = (float*)d_out;                 // 8 x 524,288 f32 conv partials
  ushort* qbb = (ushort*)((float*)d_out + 4194304);  // 8,388,608 bf16 Q

  prep_kernel<<<2560, 256, 0, stream>>>(x, xb, q_w, kv_w, out_w, conv_w,
                                        qwb, kvwb, owb, wTb);
  // conv as patch-GEMM, split-K=8 -> fp32 partials (in d_out)
  mfma_gemm<true, false, 0><<<dim3(4, 16, 8), 256, 0, stream>>>(
      xb, wTb, nullptr, part, nullptr, nullptr, 4096, 512, 256, 524288);
  // fused reduce + bias + LayerNorm -> x1b bf16
  ln_fused<<<2048, 256, 0, stream>>>(part, conv_b, ln_g, ln_b, x1b);
  // KV projection -> K bf16 (kb) + V^T bf16 (vT)
  mfma_gemm<false, true, 2><<<dim3(8, 16, 1), 256, 0, stream>>>(
      x1b, kvwb, kv_b, nullptr, kb, vT, 256, 256, 512, 0);
  // Q projection -> qbb bf16 (upper half of d_out)
  breg_gemm<false><<<dim3(4, 128), 256, 0, stream>>>(xb, qwb, q_b, nullptr, qbb);
  // MFMA flash attention -> aob bf16 (aliases xb; xb dead after Q proj)
  attn_mfma<<<1024, 256, 0, stream>>>(qbb, kb, vT, aob);
  // output projection -> d_out fp32 (overwrites the scratch halves)
  breg_gemm<true><<<dim3(4, 128), 256, 0, stream>>>(aob, owb, out_b, (float*)d_out, nullptr);
}